// Round 14
// baseline (172.689 us; speedup 1.0000x reference)
//
#include <hip/hip_runtime.h>

typedef unsigned short ushort_t;
typedef unsigned int uint_t;
typedef __attribute__((ext_vector_type(8))) unsigned short ushort8;
typedef __attribute__((ext_vector_type(2))) unsigned int uint2v;
typedef __attribute__((ext_vector_type(8))) __bf16 bf16x8;
typedef __attribute__((ext_vector_type(4))) float floatx4;

#define DIM 768
#define NHEAD 12
#define DHEAD 64
#define SEQ 1024
#define BATCH 4
#define TOKENS (BATCH * SEQ)
#define WELEM (DIM * DIM)
// SCALE * log2(e) = 0.125 * 1.4426950409
#define SCALE_LOG2E 0.18033688011112042f

static __device__ __forceinline__ uint_t fbits(float f) {
  union { float f; uint_t u; } c; c.f = f; return c.u;
}
static __device__ __forceinline__ ushort_t f2bf(float f) {
  return (ushort_t)((fbits(f) + 0x8000u) >> 16);
}
static __device__ __forceinline__ uint_t pack_bf2(float lo, float hi) {
  const uint_t a = fbits(lo) + 0x8000u, b = fbits(hi) + 0x8000u;
#if __has_builtin(__builtin_amdgcn_perm)
  return __builtin_amdgcn_perm(b, a, 0x07060302u);
#else
  return (a >> 16) | (b & 0xFFFF0000u);
#endif
}
static __device__ __forceinline__ float fexp2(float x) {
#if __has_builtin(__builtin_amdgcn_exp2f)
  return __builtin_amdgcn_exp2f(x);
#else
  return exp2f(x);
#endif
}
static __device__ __forceinline__ floatx4 mfma16(ushort8 a, ushort8 b, floatx4 c) {
  return __builtin_amdgcn_mfma_f32_16x16x32_bf16(
      __builtin_bit_cast(bf16x8, a), __builtin_bit_cast(bf16x8, b), c, 0, 0, 0);
}
// async global->LDS, 16B/lane, dest = wave-uniform base + lane*16
static __device__ __forceinline__ void gload_lds16(const ushort_t* g,
                                                   ushort_t* l) {
  __builtin_amdgcn_global_load_lds(
      (const __attribute__((address_space(1))) void*)g,
      (__attribute__((address_space(3))) void*)l, 16, 0, 0);
}

// ---------------- prep: weight fp32->bf16 (blocks 0..2303) + LN (2304..3327) -
__global__ __launch_bounds__(256) void prep_kernel(
    const float* __restrict__ qw, const float* __restrict__ kw,
    const float* __restrict__ vw, const float* __restrict__ pw,
    const float* __restrict__ x, ushort_t* __restrict__ wbf,
    ushort_t* __restrict__ xn) {
  const int bid = blockIdx.x;
  if (bid < 2304) {
    const int mat = bid / 576, inner = bid % 576;
    const float* s = (mat == 0) ? qw : (mat == 1) ? kw : (mat == 2) ? vw : pw;
    ushort_t* d = wbf + (size_t)mat * WELEM;
    const int i = (inner * 256 + threadIdx.x) * 4;
    const float4 f = *(const float4*)&s[i];
    uint2v o;
    o[0] = pack_bf2(f.x, f.y);
    o[1] = pack_bf2(f.z, f.w);
    *(uint2v*)&d[i] = o;
  } else {
    const int wave = threadIdx.x >> 6, lane = threadIdx.x & 63;
    const int row = (bid - 2304) * 4 + wave;
    const float4* xr = (const float4*)(x + (size_t)row * DIM);
    float4 v[3];
    float s = 0.f, s2 = 0.f;
#pragma unroll
    for (int j = 0; j < 3; ++j) {
      v[j] = xr[j * 64 + lane];
      s += v[j].x + v[j].y + v[j].z + v[j].w;
      s2 += v[j].x * v[j].x + v[j].y * v[j].y + v[j].z * v[j].z +
            v[j].w * v[j].w;
    }
#pragma unroll
    for (int off = 1; off < 64; off <<= 1) {
      s += __shfl_xor(s, off);
      s2 += __shfl_xor(s2, off);
    }
    const float mean = s * (1.f / 768.f);
    const float var = (s2 - 768.f * mean * mean) * (1.f / 767.f);  // ddof=1
    const float rstd = rsqrtf(var);
    ushort_t* xo = xn + (size_t)row * DIM;
#pragma unroll
    for (int j = 0; j < 3; ++j) {
      uint2v o;
      o[0] = pack_bf2((v[j].x - mean) * rstd, (v[j].y - mean) * rstd);
      o[1] = pack_bf2((v[j].z - mean) * rstd, (v[j].w - mean) * rstd);
      *(uint2v*)&xo[(j * 64 + lane) * 4] = o;
    }
  }
}

// ---------------- QKV GEMM v6: producer/consumer wave pipeline ---------------
// grid (64, 18), 320 threads = 4 consumer waves + 1 producer wave.
// Producer owns ALL global_load_lds + s_waitcnt vmcnt(24) + LDS flag writes
// (per-wave vmcnt -> the compiler cannot tie consumer ds_reads to it).
// Consumers poll LDS flags; NO __syncthreads in the loop. Ring of 3 tiles.
// Consumer tile = round-12's proven 64 tok x 128 ch, swapped-operand MFMA.
#define BK 64
#define NKIT (DIM / BK)
#define RING 3
__global__ __launch_bounds__(320) void qkv_kernel(
    const ushort_t* __restrict__ xn, const ushort_t* __restrict__ wbf,
    const float* __restrict__ qb, const float* __restrict__ kb,
    const float* __restrict__ vb,
    ushort_t* __restrict__ qh, ushort_t* __restrict__ kh,
    ushort_t* __restrict__ vt) {
  __shared__ ushort_t As[RING][64 * BK];    // tokens, 3 x 8 KB
  __shared__ ushort_t Bs[RING][128 * BK];   // W channels, 3 x 16 KB
  __shared__ int flag[RING];                // flag[s] = t+1 when tile t ready
  __shared__ int done[RING];                // cumulative consumer completions
  const int tid = threadIdx.x;
  const int wave = tid >> 6, lane = tid & 63, quad = lane >> 4, l15 = lane & 15;
  const int m0 = blockIdx.x * 64;                // token block
  const int mat = blockIdx.y / 6, nb = blockIdx.y % 6;
  const int n0 = nb * 128;                       // channel block
  const ushort_t* W = wbf + (size_t)mat * WELEM;
  const int srow8 = lane >> 3;
  const int schunk = (lane & 7) ^ srow8;
  const int l7 = l15 & 7;

  if (tid < RING) { flag[tid] = 0; done[tid] = 0; }
  __syncthreads();   // the only barrier: flag/done init visible

  if (wave == 4) {
    // ---------------- producer ----------------
    for (int t = 0; t <= NKIT; ++t) {
      if (t < NKIT) {
        if (t >= RING) {                      // wait slot free
          const int need = 4 * (t / RING);
          int g = 0;
          while (__atomic_load_n(&done[t % RING], __ATOMIC_RELAXED) < need &&
                 ++g < (1 << 22)) {}
        }
        const int k0 = t * BK, s = t % RING;
#pragma unroll
        for (int c = 0; c < 8; ++c)           // As: 8 x 1KB wave-chunks
          gload_lds16(&xn[(size_t)(m0 + c * 8 + srow8) * DIM + k0 + schunk * 8],
                      &As[s][c * 512]);
#pragma unroll
        for (int c = 0; c < 16; ++c)          // Bs: 16 x 1KB wave-chunks
          gload_lds16(&W[(size_t)(n0 + c * 8 + srow8) * DIM + k0 + schunk * 8],
                      &Bs[s][c * 512]);
      }
      if (t >= 1) {
        if (t < NKIT)
          __builtin_amdgcn_s_waitcnt(0x4F78); // vmcnt(24): tile t-1 landed
        else
          __builtin_amdgcn_s_waitcnt(0x0F70); // vmcnt(0): last tile landed
        __atomic_store_n(&flag[(t - 1) % RING], t, __ATOMIC_RELAXED);
      }
    }
    return;
  }

  // ---------------- consumers (waves 0..3) ----------------
  const int chan_off = (wave >> 1) * 64, tok_off = (wave & 1) * 32;
  floatx4 acc[4][2];
#pragma unroll
  for (int i = 0; i < 4; ++i)
#pragma unroll
    for (int j = 0; j < 2; ++j) acc[i][j] = (floatx4){0.f, 0.f, 0.f, 0.f};

  for (int t = 0; t < NKIT; ++t) {
    const int s = t % RING;
    {
      int g = 0;
      while (__atomic_load_n(&flag[s], __ATOMIC_RELAXED) < t + 1 &&
             ++g < (1 << 22)) {}
    }
    ushort8 af[2][2], bfr[4][2];
#pragma unroll
    for (int k2 = 0; k2 < 2; ++k2) {
      const int ch = ((k2 * 4 + quad) ^ l7) * 8;
#pragma unroll
      for (int j = 0; j < 2; ++j)
        af[j][k2] = *(const ushort8*)&As[s][(tok_off + j * 16 + l15) * BK + ch];
#pragma unroll
      for (int i = 0; i < 4; ++i)
        bfr[i][k2] = *(const ushort8*)&Bs[s][(chan_off + i * 16 + l15) * BK + ch];
    }
#pragma unroll
    for (int k2 = 0; k2 < 2; ++k2)
#pragma unroll
      for (int i = 0; i < 4; ++i)
#pragma unroll
        for (int j = 0; j < 2; ++j)
          acc[i][j] = mfma16(bfr[i][k2], af[j][k2], acc[i][j]);
    __builtin_amdgcn_s_waitcnt(0xC07F);   // lgkmcnt(0): my ds_reads retired
    __atomic_fetch_add(&done[s], 1, __ATOMIC_RELAXED);
  }

  if (mat != 2) {
    const float* bias = (mat == 0) ? qb : kb;
    ushort_t* dst = (mat == 0) ? qh : kh;
    const float os = (mat == 0) ? SCALE_LOG2E : 1.0f;
    const int hh = (n0 + chan_off) >> 6;           // head (uniform, 64-aligned)
#pragma unroll
    for (int i = 0; i < 4; ++i) {
      const int ch0 = n0 + chan_off + i * 16 + quad * 4;  // 4 consec channels
      const float4 bv = *(const float4*)&bias[ch0];
      const int d0 = i * 16 + quad * 4;                   // = ch0 & 63
#pragma unroll
      for (int j = 0; j < 2; ++j) {
        const int tok = m0 + tok_off + j * 16 + l15;
        const int bb = tok >> 10, nn = tok & 1023;
        uint2v pk;
        pk[0] = pack_bf2((acc[i][j][0] + bv.x) * os, (acc[i][j][1] + bv.y) * os);
        pk[1] = pack_bf2((acc[i][j][2] + bv.z) * os, (acc[i][j][3] + bv.w) * os);
        *(uint2v*)&dst[(size_t)((bb * NHEAD + hh) * SEQ + nn) * DHEAD + d0] = pk;
      }
    }
  } else {
    // V sigma2: tokens {tok_off+l15, tok_off+16+l15} (same 32-group) are
    // slots l15*2, l15*2+1 -> one b32 per (i,r).
    const int tokg = m0 + tok_off;                 // 32-aligned token group
    const int bb = tokg >> 10, gg = tokg & 1023;
#pragma unroll
    for (int i = 0; i < 4; ++i) {
      const int ch0 = n0 + chan_off + i * 16 + quad * 4;
      const float4 bv = *(const float4*)&vb[ch0];
      const float bvf[4] = {bv.x, bv.y, bv.z, bv.w};
      const int hh = ch0 >> 6, d0 = ch0 & 63;
#pragma unroll
      for (int r = 0; r < 4; ++r) {
        const size_t base = (size_t)((bb * NHEAD + hh) * DHEAD + d0 + r) * SEQ;
        *(uint_t*)&vt[base + gg + l15 * 2] =
            pack_bf2(acc[i][0][r] + bvf[r], acc[i][1][r] + bvf[r]);
      }
    }
  }
}

// ---------------- Flash attention v8 (round-12): Bc=32, single-barrier dbuf --
// 1-D grid of 768 blocks w/ XCD swizzle. 256 threads = 4 waves.
// grp = wave>>1 handles keys [grp*512,+512) in Bc=32 tiles, double-buffered
// (one barrier per iter; prefetch t+1 flies during compute t). wsub = wave&1
// handles q-rows [wsub*32,+32). O,l pure sums; groups combine via LDS.
#define PSTR2 34
__global__ __launch_bounds__(256) void attn_kernel(
    const ushort_t* __restrict__ qh, const ushort_t* __restrict__ kh,
    const ushort_t* __restrict__ vt, ushort_t* __restrict__ ao) {
  __shared__ ushort_t kv[2][2][2][2048];   // [grp][buf][K,V][32x64 / 64x32]
  __shared__ ushort_t Ps[4][2][16 * PSTR2]; // [wave][wsubtile][row][32+pad]
  float* cb = (float*)&kv[0][0][0][0];     // combine buffer alias
  const int tid = threadIdx.x;
  const int wave = tid >> 6, lane = tid & 63, quad = lane >> 4, l15 = lane & 15;
  const int l7 = l15 & 7;
  const int grp = wave >> 1, wsub = wave & 1;
  // XCD swizzle: bid%8 = XCD slot; each slot covers 6 hb pairs x 16 q-blocks
  const int bid = blockIdx.x;
  const int idx = bid >> 3;                       // 0..95
  const int hb = (bid & 7) * 6 + idx % 6;         // 0..47
  const int qb = idx / 6;                         // 0..15
  const int h = hb % NHEAD, b = hb / NHEAD;
  const int basekv = ((b * NHEAD + h) * SEQ) * DHEAD;
  const int basevt = ((b * NHEAD + h) * DHEAD) * SEQ;
  const int q0 = qb * 64 + wsub * 32;
  const int kbase = grp * 512;

  ushort8 qf[2][2];
#pragma unroll
  for (int w = 0; w < 2; ++w) {
    const ushort_t* Qr = qh + basekv + (q0 + w * 16 + l15) * DHEAD;
    qf[w][0] = *(const ushort8*)&Qr[quad * 8];
    qf[w][1] = *(const ushort8*)&Qr[32 + quad * 8];
  }
  ushort8 ones;
#pragma unroll
  for (int i = 0; i < 8; ++i) ones[i] = 0x3F80;  // bf16 1.0

  floatx4 o[2][4];
#pragma unroll
  for (int w = 0; w < 2; ++w)
#pragma unroll
    for (int t = 0; t < 4; ++t) o[w][t] = (floatx4){0.f, 0.f, 0.f, 0.f};
  floatx4 acc_l[2] = {(floatx4){0.f, 0.f, 0.f, 0.f},
                      (floatx4){0.f, 0.f, 0.f, 0.f}};

  // staging lane coords
  const int ksrow = lane >> 3, kschunk = (lane & 7) ^ ksrow;   // K
  const int vdrow = lane >> 2;                                 // V: d row
  const int vchunk = (lane & 3) ^ ((vdrow >> 1) & 3);          // V: 2-way free

  auto stage = [&](int kt, int bf) {     // kt absolute
#pragma unroll
    for (int i = 0; i < 2; ++i) {
      const int c = wsub * 2 + i;        // 0..3 across group's 2 waves
      gload_lds16(&kh[basekv + (kt + c * 8 + ksrow) * DHEAD + kschunk * 8],
                  &kv[grp][bf][0][c * 512]);
      gload_lds16(&vt[basevt + (c * 16 + vdrow) * SEQ + kt + vchunk * 8],
                  &kv[grp][bf][1][c * 512]);
    }
  };

  stage(kbase, 0);
  for (int it = 0; it < 16; ++it) {
    const int cur = it & 1;
    __syncthreads();                     // buf cur landed; other buf free
    if (it + 1 < 16) stage(kbase + (it + 1) * 32, cur ^ 1);
    const ushort_t* K = &kv[grp][cur][0][0];
    const ushort_t* V = &kv[grp][cur][1][0];

    // ---- S = Q K^T : 32 q-rows x 32 keys ----------------------------------
    floatx4 sacc[2][2];
#pragma unroll
    for (int w = 0; w < 2; ++w)
#pragma unroll
      for (int s = 0; s < 2; ++s) sacc[w][s] = (floatx4){0.f, 0.f, 0.f, 0.f};
#pragma unroll
    for (int s = 0; s < 2; ++s) {
#pragma unroll
      for (int hh = 0; hh < 2; ++hh) {
        const ushort8 kf = *(const ushort8*)&K[(s * 16 + l15) * 64 +
                                               (((hh * 4 + quad) ^ l7) * 8)];
#pragma unroll
        for (int w = 0; w < 2; ++w)
          sacc[w][s] = mfma16(qf[w][hh], kf, sacc[w][s]);
      }
    }

    // ---- p = exp2(s); one b32 store per (w,r) (sigma2 layout) -------------
#pragma unroll
    for (int w = 0; w < 2; ++w)
#pragma unroll
      for (int r = 0; r < 4; ++r)
        *(uint_t*)&Ps[wave][w][(quad * 4 + r) * PSTR2 + l15 * 2] =
            pack_bf2(fexp2(sacc[w][0][r]), fexp2(sacc[w][1][r]));

    // ---- O += P V ; l += P . ones (same-wave LDS round-trip) --------------
    ushort8 pf[2];
#pragma unroll
    for (int w = 0; w < 2; ++w) {
      pf[w] = *(const ushort8*)&Ps[wave][w][l15 * PSTR2 + quad * 8];
      acc_l[w] = mfma16(pf[w], ones, acc_l[w]);
    }
#pragma unroll
    for (int t = 0; t < 4; ++t) {
      const ushort8 vf = *(const ushort8*)&V[(t * 16 + l15) * 32 +
                                             ((quad ^ ((l15 >> 1) & 3)) * 8)];
#pragma unroll
      for (int w = 0; w < 2; ++w) o[w][t] = mfma16(pf[w], vf, o[w][t]);
    }
  }
  __syncthreads();   // all compute done before cb overwrites kv

  // ---- cross-group combine via LDS (reuses kv region) ----------------------
  const int cb0 = wsub * (32 * 66);
  if (grp == 1) {
#pragma unroll
    for (int w = 0; w < 2; ++w) {
#pragma unroll
      for (int t = 0; t < 4; ++t)
#pragma unroll
        for (int r = 0; r < 4; ++r)
          cb[cb0 + (w * 16 + quad * 4 + r) * 66 + t * 16 + l15] = o[w][t][r];
      if (l15 == 0)
#pragma unroll
        for (int r = 0; r < 4; ++r)
          cb[cb0 + (w * 16 + quad * 4 + r) * 66 + 64] = acc_l[w][r];
    }
  }
  __syncthreads();
  if (grp == 0) {
#pragma unroll
    for (int w = 0; w < 2; ++w) {
#pragma unroll
      for (int r = 0; r < 4; ++r) {
        const int row = w * 16 + quad * 4 + r;
        const float l = acc_l[w][r] + cb[cb0 + row * 66 + 64];
        const float rl = 1.f / l;
        const int token = b * SEQ + q0 + row;
#pragma unroll
        for (int t = 0; t < 4; ++t) {
          const float val = o[w][t][r] + cb[cb0 + row * 66 + t * 16 + l15];
          ao[(size_t)token * DIM + h * DHEAD + t * 16 + l15] = f2bf(val * rl);
        }
      }
    }
  }
}

// ---------------- Proj GEMM v5 (round-13): 64x64 tiles, dbuf, float4 out -----
// grid (64, 12): 64 tokens x 64 channels; LDS 32 KB.
__global__ __launch_bounds__(256) void proj_kernel(
    const ushort_t* __restrict__ ao, const ushort_t* __restrict__ pwb,
    const float* __restrict__ pb, const float* __restrict__ x,
    float* __restrict__ out) {
  __shared__ ushort_t Asp[2][64 * BK];   // tokens, 2 x 8 KB
  __shared__ ushort_t Bsp[2][64 * BK];   // channels, 2 x 8 KB
  const int tid = threadIdx.x;
  const int wave = tid >> 6, lane = tid & 63, quad = lane >> 4, l15 = lane & 15;
  const int m0 = blockIdx.x * 64;                  // token block
  const int n0 = blockIdx.y * 64;                  // channel block
  const int chan_off = (wave >> 1) * 32, tok_off = (wave & 1) * 32;
  const int srow8 = lane >> 3;
  const int schunk = (lane & 7) ^ srow8;
  const int l7 = l15 & 7;

  floatx4 acc[2][2];
#pragma unroll
  for (int i = 0; i < 2; ++i)
#pragma unroll
    for (int j = 0; j < 2; ++j) acc[i][j] = (floatx4){0.f, 0.f, 0.f, 0.f};

  auto stage = [&](int k0, int bf) {
#pragma unroll
    for (int i = 0; i < 2; ++i) {
      const int c = wave * 2 + i;
      gload_lds16(&ao[(size_t)(m0 + c * 8 + srow8) * DIM + k0 + schunk * 8],
                  &Asp[bf][c * 512]);
    }
#pragma unroll
    for (int i = 0; i < 2; ++i) {
      const int c = wave * 2 + i;
      gload_lds16(&pwb[(size_t)(n0 + c * 8 + srow8) * DIM + k0 + schunk * 8],
                  &Bsp[bf][c * 512]);
    }
  };

  stage(0, 0);
  for (int it = 0; it < NKIT; ++it) {
    const int cur = it & 1;
    __syncthreads();
    if (it + 1 < NKIT) stage((it + 1) * BK, cur ^ 1);
    ushort8 af[2][2], bfr[2][2];
#pragma unroll
    for (int k2 = 0; k2 < 2; ++k2) {
      const int ch = ((k2 * 4 + quad) ^ l7) * 8;
#pragma unroll
      for (int j = 0; j < 2; ++j)
        af[j][k2] = *(const ushort8*)&Asp[cur][(tok_off + j * 16 + l15) * BK + ch];
#pragma unroll
      for (int i = 0; i < 2; ++i)
        bfr[i][k2] = *(const ushort8*)&Bsp[cur][(chan_off + i * 16 + l15) * BK + ch];
    }
#pragma unroll
    for (int k2 = 0; k2 < 2; ++k2)
#pragma unroll
      for (int i = 0; i < 2; ++i)
#pragma unroll
        for (int j = 0; j < 2; ++j)
          acc[i][j] = mfma16(bfr[i][k2], af[j][k2], acc[i][j]);
  }

#pragma unroll
  for (int i = 0; i < 2; ++i) {
    const int ch0 = n0 + chan_off + i * 16 + quad * 4;   // 4 consec channels
    const float4 bv = *(const float4*)&pb[ch0];
#pragma unroll
    for (int j = 0; j < 2; ++j) {
      const int tok = m0 + tok_off + j * 16 + l15;
      const float4 res = *(const float4*)&x[(size_t)tok * DIM + ch0];
      float4 ov;
      ov.x = acc[i][j][0] + bv.x + res.x;
      ov.y = acc[i][j][1] + bv.y + res.y;
      ov.z = acc[i][j][2] + bv.z + res.z;
      ov.w = acc[i][j][3] + bv.w + res.w;
      *(float4*)&out[(size_t)tok * DIM + ch0] = ov;
    }
  }
}

extern "C" void kernel_launch(void* const* d_in, const int* in_sizes, int n_in,
                              void* d_out, int out_size, void* d_ws,
                              size_t ws_size, hipStream_t stream) {
  const float* x  = (const float*)d_in[0];
  const float* qw = (const float*)d_in[1];
  const float* kw = (const float*)d_in[2];
  const float* vw = (const float*)d_in[3];
  const float* qb = (const float*)d_in[4];
  const float* kb = (const float*)d_in[5];
  const float* vb = (const float*)d_in[6];
  const float* pw = (const float*)d_in[7];
  const float* pb = (const float*)d_in[8];
  float* out = (float*)d_out;

  ushort_t* ws = (ushort_t*)d_ws;
  const size_t NTOK = (size_t)TOKENS * DIM;
  ushort_t* xn  = ws;
  ushort_t* qh  = ws + NTOK;
  ushort_t* kh  = ws + 2 * NTOK;
  ushort_t* vt  = ws + 3 * NTOK;             // V^T [b][h][d][n], sigma2-permuted
  ushort_t* wbf = ws + 4 * NTOK;             // 4 bf16 weight matrices
  ushort_t* ao  = xn;                        // xn dead after qkv; reuse

  prep_kernel<<<2304 + TOKENS / 4, 256, 0, stream>>>(qw, kw, vw, pw, x, wbf, xn);
  qkv_kernel<<<dim3(64, 18), 320, 0, stream>>>(xn, wbf, qb, kb, vb, qh, kh, vt);
  attn_kernel<<<768, 256, 0, stream>>>(qh, kh, vt, ao);
  proj_kernel<<<dim3(64, 12), 256, 0, stream>>>(ao, wbf + 3 * (size_t)WELEM, pb,
                                                x, out);
}

// Round 15
// 152.742 us; speedup vs baseline: 1.1306x; 1.1306x over previous
//
#include <hip/hip_runtime.h>

typedef unsigned short ushort_t;
typedef unsigned int uint_t;
typedef __attribute__((ext_vector_type(8))) unsigned short ushort8;
typedef __attribute__((ext_vector_type(2))) unsigned int uint2v;
typedef __attribute__((ext_vector_type(8))) __bf16 bf16x8;
typedef __attribute__((ext_vector_type(4))) float floatx4;

#define DIM 768
#define NHEAD 12
#define DHEAD 64
#define SEQ 1024
#define BATCH 4
#define TOKENS (BATCH * SEQ)
#define WELEM (DIM * DIM)
// SCALE * log2(e) = 0.125 * 1.4426950409
#define SCALE_LOG2E 0.18033688011112042f

static __device__ __forceinline__ uint_t fbits(float f) {
  union { float f; uint_t u; } c; c.f = f; return c.u;
}
static __device__ __forceinline__ ushort_t f2bf(float f) {
  return (ushort_t)((fbits(f) + 0x8000u) >> 16);
}
static __device__ __forceinline__ uint_t pack_bf2(float lo, float hi) {
  const uint_t a = fbits(lo) + 0x8000u, b = fbits(hi) + 0x8000u;
#if __has_builtin(__builtin_amdgcn_perm)
  return __builtin_amdgcn_perm(b, a, 0x07060302u);
#else
  return (a >> 16) | (b & 0xFFFF0000u);
#endif
}
static __device__ __forceinline__ float fexp2(float x) {
#if __has_builtin(__builtin_amdgcn_exp2f)
  return __builtin_amdgcn_exp2f(x);
#else
  return exp2f(x);
#endif
}
static __device__ __forceinline__ floatx4 mfma16(ushort8 a, ushort8 b, floatx4 c) {
  return __builtin_amdgcn_mfma_f32_16x16x32_bf16(
      __builtin_bit_cast(bf16x8, a), __builtin_bit_cast(bf16x8, b), c, 0, 0, 0);
}
// async global->LDS, 16B/lane, dest = wave-uniform base + lane*16
static __device__ __forceinline__ void gload_lds16(const ushort_t* g,
                                                   ushort_t* l) {
  __builtin_amdgcn_global_load_lds(
      (const __attribute__((address_space(1))) void*)g,
      (__attribute__((address_space(3))) void*)l, 16, 0, 0);
}

// ---------------- prep: weight fp32->bf16 (blocks 0..2303) + LN (2304..3327) -
__global__ __launch_bounds__(256) void prep_kernel(
    const float* __restrict__ qw, const float* __restrict__ kw,
    const float* __restrict__ vw, const float* __restrict__ pw,
    const float* __restrict__ x, ushort_t* __restrict__ wbf,
    ushort_t* __restrict__ xn) {
  const int bid = blockIdx.x;
  if (bid < 2304) {
    const int mat = bid / 576, inner = bid % 576;
    const float* s = (mat == 0) ? qw : (mat == 1) ? kw : (mat == 2) ? vw : pw;
    ushort_t* d = wbf + (size_t)mat * WELEM;
    const int i = (inner * 256 + threadIdx.x) * 4;
    const float4 f = *(const float4*)&s[i];
    uint2v o;
    o[0] = pack_bf2(f.x, f.y);
    o[1] = pack_bf2(f.z, f.w);
    *(uint2v*)&d[i] = o;
  } else {
    const int wave = threadIdx.x >> 6, lane = threadIdx.x & 63;
    const int row = (bid - 2304) * 4 + wave;
    const float4* xr = (const float4*)(x + (size_t)row * DIM);
    float4 v[3];
    float s = 0.f, s2 = 0.f;
#pragma unroll
    for (int j = 0; j < 3; ++j) {
      v[j] = xr[j * 64 + lane];
      s += v[j].x + v[j].y + v[j].z + v[j].w;
      s2 += v[j].x * v[j].x + v[j].y * v[j].y + v[j].z * v[j].z +
            v[j].w * v[j].w;
    }
#pragma unroll
    for (int off = 1; off < 64; off <<= 1) {
      s += __shfl_xor(s, off);
      s2 += __shfl_xor(s2, off);
    }
    const float mean = s * (1.f / 768.f);
    const float var = (s2 - 768.f * mean * mean) * (1.f / 767.f);  // ddof=1
    const float rstd = rsqrtf(var);
    ushort_t* xo = xn + (size_t)row * DIM;
#pragma unroll
    for (int j = 0; j < 3; ++j) {
      uint2v o;
      o[0] = pack_bf2((v[j].x - mean) * rstd, (v[j].y - mean) * rstd);
      o[1] = pack_bf2((v[j].z - mean) * rstd, (v[j].w - mean) * rstd);
      *(uint2v*)&xo[(j * 64 + lane) * 4] = o;
    }
  }
}

// ---------------- QKV GEMM (round-9 dbuf structure, V epilogue coalesced) ----
// grid (32, 18): x = token block (128), y = matrix(3) * channel-block(6).
// Swapped-operand MFMA: C[m=channel][n=token]. One barrier/iter dbuf.
// mat 0/1: packed b64 stores to [b][h][n][d] (Q pre-scaled by SCALE*log2e).
// mat 2 (V): [b][h][d][n] with sigma4 slot permutation; a thread's 4 j-values
// (tokens 16 apart in one 64-group) are slots l15*4+{0..3} -> packed b64.
#define BK 64
#define NKIT (DIM / BK)
__global__ __launch_bounds__(256) void qkv_kernel(
    const ushort_t* __restrict__ xn, const ushort_t* __restrict__ wbf,
    const float* __restrict__ qb, const float* __restrict__ kb,
    const float* __restrict__ vb,
    ushort_t* __restrict__ qh, ushort_t* __restrict__ kh,
    ushort_t* __restrict__ vt) {
  __shared__ ushort_t As[2][128 * BK];   // tokens (2 x 16 KB)
  __shared__ ushort_t Bs[2][128 * BK];   // W channels (2 x 16 KB)
  const int tid = threadIdx.x;
  const int wave = tid >> 6, lane = tid & 63, quad = lane >> 4, l15 = lane & 15;
  const int m0 = blockIdx.x * 128;               // token block
  const int mat = blockIdx.y / 6, nb = blockIdx.y % 6;
  const int n0 = nb * 128;                       // channel block
  const ushort_t* W = wbf + (size_t)mat * WELEM;
  const int chan_off = (wave >> 1) * 64, tok_off = (wave & 1) * 64;
  const int srow8 = lane >> 3;
  const int schunk = (lane & 7) ^ srow8;
  const int l7 = l15 & 7;

  floatx4 acc[4][4];
#pragma unroll
  for (int i = 0; i < 4; ++i)
#pragma unroll
    for (int j = 0; j < 4; ++j) acc[i][j] = (floatx4){0.f, 0.f, 0.f, 0.f};

  auto stage = [&](int k0, int bf) {
#pragma unroll
    for (int i = 0; i < 4; ++i) {
      const int c = wave * 4 + i;
      const int row = c * 8 + srow8;
      gload_lds16(&xn[(size_t)(m0 + row) * DIM + k0 + schunk * 8],
                  &As[bf][c * 512]);
      gload_lds16(&W[(size_t)(n0 + row) * DIM + k0 + schunk * 8],
                  &Bs[bf][c * 512]);
    }
  };

  stage(0, 0);
  for (int it = 0; it < NKIT; ++it) {
    const int cur = it & 1;
    __syncthreads();                       // buf cur landed; other buf free
    if (it + 1 < NKIT) stage((it + 1) * BK, cur ^ 1);
    ushort8 af[4][2], bfr[4][2];
#pragma unroll
    for (int i = 0; i < 4; ++i)
#pragma unroll
      for (int k2 = 0; k2 < 2; ++k2) {
        const int ch = ((k2 * 4 + quad) ^ l7) * 8;
        bfr[i][k2] = *(const ushort8*)&Bs[cur][(chan_off + i * 16 + l15) * BK + ch];
        af[i][k2] = *(const ushort8*)&As[cur][(tok_off + i * 16 + l15) * BK + ch];
      }
#pragma unroll
    for (int k2 = 0; k2 < 2; ++k2)
#pragma unroll
      for (int i = 0; i < 4; ++i)
#pragma unroll
        for (int j = 0; j < 4; ++j)
          acc[i][j] = mfma16(bfr[i][k2], af[j][k2], acc[i][j]);
  }

  if (mat != 2) {
    const float* bias = (mat == 0) ? qb : kb;
    ushort_t* dst = (mat == 0) ? qh : kh;
    const float os = (mat == 0) ? SCALE_LOG2E : 1.0f;
    const int hh = (n0 + chan_off) >> 6;           // head (uniform, 64-aligned)
#pragma unroll
    for (int i = 0; i < 4; ++i) {
      const int ch0 = n0 + chan_off + i * 16 + quad * 4;  // 4 consec channels
      const float4 bv = *(const float4*)&bias[ch0];
      const int d0 = i * 16 + quad * 4;
#pragma unroll
      for (int j = 0; j < 4; ++j) {
        const int tok = m0 + tok_off + j * 16 + l15;
        const int bb = tok >> 10, nn = tok & 1023;
        uint2v pk;
        pk[0] = pack_bf2((acc[i][j][0] + bv.x) * os, (acc[i][j][1] + bv.y) * os);
        pk[1] = pack_bf2((acc[i][j][2] + bv.z) * os, (acc[i][j][3] + bv.w) * os);
        *(uint2v*)&dst[(size_t)((bb * NHEAD + hh) * SEQ + nn) * DHEAD + d0] = pk;
      }
    }
  } else {
    // V: tokens {l15, l15+16, l15+32, l15+48} of 64-group (m0+tok_off) are
    // sigma4 slots l15*4..+3 -> one b64 per (i,r), fully coalesced.
    const int tokg = m0 + tok_off;                 // 64-aligned token group
    const int bb = tokg >> 10, gg = tokg & 1023;
#pragma unroll
    for (int i = 0; i < 4; ++i) {
      const int ch0 = n0 + chan_off + i * 16 + quad * 4;
      const float4 bv = *(const float4*)&vb[ch0];
      const float bvf[4] = {bv.x, bv.y, bv.z, bv.w};
      const int hh = ch0 >> 6, d0 = ch0 & 63;
#pragma unroll
      for (int r = 0; r < 4; ++r) {
        const size_t base = (size_t)((bb * NHEAD + hh) * DHEAD + d0 + r) * SEQ;
        uint2v pk;
        pk[0] = pack_bf2(acc[i][0][r] + bvf[r], acc[i][1][r] + bvf[r]);
        pk[1] = pack_bf2(acc[i][2][r] + bvf[r], acc[i][3][r] + bvf[r]);
        *(uint2v*)&vt[base + gg + l15 * 4] = pk;
      }
    }
  }
}

// ---------------- Flash attention v6 + XCD-locality swizzle ------------------
// 1-D grid of 768 blocks; decode so each XCD (assuming linear%8 round-robin)
// owns 6 (head,batch) pairs for ALL 16 q-blocks -> per-XCD K/V set 1.5 MB
// fits L2. 256 threads = 4 waves; 64 q-rows/block; wave group g = wave>>1
// handles keys [g*512, +512), wsub = wave&1 handles q-rows [wsub*32, +32).
// O,l pure sums (no-max softmax); groups combine additively via LDS.
#define PSTR 68
__global__ __launch_bounds__(256) void attn_kernel(
    const ushort_t* __restrict__ qh, const ushort_t* __restrict__ kh,
    const ushort_t* __restrict__ vt, ushort_t* __restrict__ ao) {
  __shared__ ushort_t kv[2][2][4096];    // [grp][K,V][64 rows x 64]
  __shared__ ushort_t Ps[4][16 * PSTR];  // per-wave P buffer
  float* cb = (float*)&kv[0][0][0];      // combine buffer alias (32 KB)
  const int tid = threadIdx.x;
  const int wave = tid >> 6, lane = tid & 63, quad = lane >> 4, l15 = lane & 15;
  const int l7 = l15 & 7;
  const int grp = wave >> 1, wsub = wave & 1;
  // XCD swizzle: bid%8 = XCD slot; each slot covers 6 hb pairs x 16 q-blocks
  const int bid = blockIdx.x;
  const int idx = bid >> 3;                       // 0..95
  const int hb = (bid & 7) * 6 + idx % 6;         // 0..47
  const int qb = idx / 6;                         // 0..15
  const int h = hb % NHEAD, b = hb / NHEAD;
  const int basekv = ((b * NHEAD + h) * SEQ) * DHEAD;
  const int basevt = ((b * NHEAD + h) * DHEAD) * SEQ;
  const int q0 = qb * 64 + wsub * 32;
  const int kbase = grp * 512;

  ushort8 qf[2][2];
#pragma unroll
  for (int w = 0; w < 2; ++w) {
    const ushort_t* Qr = qh + basekv + (q0 + w * 16 + l15) * DHEAD;
    qf[w][0] = *(const ushort8*)&Qr[quad * 8];
    qf[w][1] = *(const ushort8*)&Qr[32 + quad * 8];
  }
  ushort8 ones;
#pragma unroll
  for (int i = 0; i < 8; ++i) ones[i] = 0x3F80;  // bf16 1.0

  floatx4 o[2][4];
#pragma unroll
  for (int w = 0; w < 2; ++w)
#pragma unroll
    for (int t = 0; t < 4; ++t) o[w][t] = (floatx4){0.f, 0.f, 0.f, 0.f};
  floatx4 acc_l[2] = {(floatx4){0.f, 0.f, 0.f, 0.f},
                      (floatx4){0.f, 0.f, 0.f, 0.f}};

  const int srow8 = lane >> 3, schunk = (lane & 7) ^ srow8;

  for (int kt = 0; kt < 512; kt += 64) {
    // ---- stage this group's K and V^T tiles (8 gloads/wave) ----------------
#pragma unroll
    for (int i = 0; i < 4; ++i) {
      const int c = wsub * 4 + i;          // 0..7 across group's 2 waves
      gload_lds16(&kh[basekv + (kbase + kt + c * 8 + srow8) * DHEAD + schunk * 8],
                  &kv[grp][0][c * 512]);
      gload_lds16(&vt[basevt + (c * 8 + srow8) * SEQ + kbase + kt + schunk * 8],
                  &kv[grp][1][c * 512]);
    }
    __syncthreads();

    // ---- S = Q K^T : 32 q-rows x 64 keys ----------------------------------
    floatx4 sacc[2][4];
#pragma unroll
    for (int w = 0; w < 2; ++w)
#pragma unroll
      for (int s = 0; s < 4; ++s) sacc[w][s] = (floatx4){0.f, 0.f, 0.f, 0.f};
#pragma unroll
    for (int s = 0; s < 4; ++s) {
#pragma unroll
      for (int hh = 0; hh < 2; ++hh) {
        const ushort8 kf = *(const ushort8*)&kv[grp][0][(s * 16 + l15) * 64 +
                                                        (((hh * 4 + quad) ^ l7) * 8)];
#pragma unroll
        for (int w = 0; w < 2; ++w)
          sacc[w][s] = mfma16(qf[w][hh], kf, sacc[w][s]);
      }
    }

    // ---- p = exp2(s); packed b64 store into slot-permuted P ---------------
#pragma unroll
    for (int w = 0; w < 2; ++w) {
#pragma unroll
      for (int r = 0; r < 4; ++r) {
        uint2v pk;
        pk[0] = pack_bf2(fexp2(sacc[w][0][r]), fexp2(sacc[w][1][r]));
        pk[1] = pack_bf2(fexp2(sacc[w][2][r]), fexp2(sacc[w][3][r]));
        *(uint2v*)&Ps[wave][(quad * 4 + r) * PSTR + l15 * 4] = pk;
      }
    }

    // ---- O += P V ; l += P . ones -----------------------------------------
#pragma unroll
    for (int hh = 0; hh < 2; ++hh) {
      ushort8 pf[2];
#pragma unroll
      for (int w = 0; w < 2; ++w) {
        pf[w] = *(const ushort8*)&Ps[wave][l15 * PSTR + hh * 32 + quad * 8];
        acc_l[w] = mfma16(pf[w], ones, acc_l[w]);
      }
#pragma unroll
      for (int t = 0; t < 4; ++t) {
        const ushort8 vf = *(const ushort8*)&kv[grp][1][(t * 16 + l15) * 64 +
                                                        (((hh * 4 + quad) ^ l7) * 8)];
#pragma unroll
        for (int w = 0; w < 2; ++w) o[w][t] = mfma16(pf[w], vf, o[w][t]);
      }
    }
    __syncthreads();
  }

  // ---- cross-group combine via LDS (reuses kv region) ----------------------
  const int cb0 = wsub * (32 * 66);
  if (grp == 1) {
#pragma unroll
    for (int w = 0; w < 2; ++w) {
#pragma unroll
      for (int t = 0; t < 4; ++t)
#pragma unroll
        for (int r = 0; r < 4; ++r)
          cb[cb0 + (w * 16 + quad * 4 + r) * 66 + t * 16 + l15] = o[w][t][r];
      if (l15 == 0)
#pragma unroll
        for (int r = 0; r < 4; ++r)
          cb[cb0 + (w * 16 + quad * 4 + r) * 66 + 64] = acc_l[w][r];
    }
  }
  __syncthreads();
  if (grp == 0) {
#pragma unroll
    for (int w = 0; w < 2; ++w) {
#pragma unroll
      for (int r = 0; r < 4; ++r) {
        const int row = w * 16 + quad * 4 + r;
        const float l = acc_l[w][r] + cb[cb0 + row * 66 + 64];
        const float rl = 1.f / l;
        const int token = b * SEQ + q0 + row;
#pragma unroll
        for (int t = 0; t < 4; ++t) {
          const float val = o[w][t][r] + cb[cb0 + row * 66 + t * 16 + l15];
          ao[(size_t)token * DIM + h * DHEAD + t * 16 + l15] = f2bf(val * rl);
        }
      }
    }
  }
}

// ---------------- Proj GEMM (round-9 dbuf), swapped, float4 out --------------
// grid (64, 6): 64 tokens x 128 channels per block
__global__ __launch_bounds__(256) void proj_kernel(
    const ushort_t* __restrict__ ao, const ushort_t* __restrict__ pwb,
    const float* __restrict__ pb, const float* __restrict__ x,
    float* __restrict__ out) {
  __shared__ ushort_t As[2][64 * BK];    // tokens, 2 x 8 KB
  __shared__ ushort_t Bs[2][128 * BK];   // channels, 2 x 16 KB
  const int tid = threadIdx.x;
  const int wave = tid >> 6, lane = tid & 63, quad = lane >> 4, l15 = lane & 15;
  const int m0 = blockIdx.x * 64;                  // token block
  const int n0 = blockIdx.y * 128;                 // channel block
  const int chan_off = (wave >> 1) * 64, tok_off = (wave & 1) * 32;
  const int srow8 = lane >> 3;
  const int schunk = (lane & 7) ^ srow8;
  const int l7 = l15 & 7;

  floatx4 acc[4][2];
#pragma unroll
  for (int i = 0; i < 4; ++i)
#pragma unroll
    for (int j = 0; j < 2; ++j) acc[i][j] = (floatx4){0.f, 0.f, 0.f, 0.f};

  auto stage = [&](int k0, int bf) {
#pragma unroll
    for (int i = 0; i < 2; ++i) {       // As: 8 chunks, 2/wave
      const int c = wave * 2 + i;
      const int row = c * 8 + srow8;
      gload_lds16(&ao[(size_t)(m0 + row) * DIM + k0 + schunk * 8],
                  &As[bf][c * 512]);
    }
#pragma unroll
    for (int i = 0; i < 4; ++i) {       // Bs: 16 chunks, 4/wave
      const int c = wave * 4 + i;
      const int row = c * 8 + srow8;
      gload_lds16(&pwb[(size_t)(n0 + row) * DIM + k0 + schunk * 8],
                  &Bs[bf][c * 512]);
    }
  };

  stage(0, 0);
  for (int it = 0; it < NKIT; ++it) {
    const int cur = it & 1;
    __syncthreads();
    if (it + 1 < NKIT) stage((it + 1) * BK, cur ^ 1);
    ushort8 af[2][2], bfr[4][2];
#pragma unroll
    for (int k2 = 0; k2 < 2; ++k2) {
      const int ch = ((k2 * 4 + quad) ^ l7) * 8;
#pragma unroll
      for (int j = 0; j < 2; ++j)
        af[j][k2] = *(const ushort8*)&As[cur][(tok_off + j * 16 + l15) * BK + ch];
#pragma unroll
      for (int i = 0; i < 4; ++i)
        bfr[i][k2] = *(const ushort8*)&Bs[cur][(chan_off + i * 16 + l15) * BK + ch];
    }
#pragma unroll
    for (int k2 = 0; k2 < 2; ++k2)
#pragma unroll
      for (int i = 0; i < 4; ++i)
#pragma unroll
        for (int j = 0; j < 2; ++j)
          acc[i][j] = mfma16(bfr[i][k2], af[j][k2], acc[i][j]);
  }

#pragma unroll
  for (int i = 0; i < 4; ++i) {
    const int ch0 = n0 + chan_off + i * 16 + quad * 4;   // 4 consec channels
    const float4 bv = *(const float4*)&pb[ch0];
#pragma unroll
    for (int j = 0; j < 2; ++j) {
      const int tok = m0 + tok_off + j * 16 + l15;
      const float4 res = *(const float4*)&x[(size_t)tok * DIM + ch0];
      float4 ov;
      ov.x = acc[i][j][0] + bv.x + res.x;
      ov.y = acc[i][j][1] + bv.y + res.y;
      ov.z = acc[i][j][2] + bv.z + res.z;
      ov.w = acc[i][j][3] + bv.w + res.w;
      *(float4*)&out[(size_t)tok * DIM + ch0] = ov;
    }
  }
}

extern "C" void kernel_launch(void* const* d_in, const int* in_sizes, int n_in,
                              void* d_out, int out_size, void* d_ws,
                              size_t ws_size, hipStream_t stream) {
  const float* x  = (const float*)d_in[0];
  const float* qw = (const float*)d_in[1];
  const float* kw = (const float*)d_in[2];
  const float* vw = (const float*)d_in[3];
  const float* qb = (const float*)d_in[4];
  const float* kb = (const float*)d_in[5];
  const float* vb = (const float*)d_in[6];
  const float* pw = (const float*)d_in[7];
  const float* pb = (const float*)d_in[8];
  float* out = (float*)d_out;

  ushort_t* ws = (ushort_t*)d_ws;
  const size_t NTOK = (size_t)TOKENS * DIM;
  ushort_t* xn  = ws;
  ushort_t* qh  = ws + NTOK;
  ushort_t* kh  = ws + 2 * NTOK;
  ushort_t* vt  = ws + 3 * NTOK;             // V^T [b][h][d][n], sigma4-permuted
  ushort_t* wbf = ws + 4 * NTOK;             // 4 bf16 weight matrices
  ushort_t* ao  = xn;                        // xn dead after qkv; reuse

  prep_kernel<<<2304 + TOKENS / 4, 256, 0, stream>>>(qw, kw, vw, pw, x, wbf, xn);
  qkv_kernel<<<dim3(32, 18), 256, 0, stream>>>(xn, wbf, qb, kb, vb, qh, kh, vt);
  attn_kernel<<<768, 256, 0, stream>>>(qh, kh, vt, ao);
  proj_kernel<<<dim3(64, 6), 256, 0, stream>>>(ao, wbf + 3 * (size_t)WELEM, pb,
                                               x, out);
}